// Round 7
// baseline (153.405 us; speedup 1.0000x reference)
//
#include <hip/hip_runtime.h>

#define DDIM 128

typedef __bf16 bf16x8 __attribute__((ext_vector_type(8)));
typedef float  floatx4 __attribute__((ext_vector_type(4)));

__device__ inline unsigned short f2bf(float f) {      // RNE fp32 -> bf16 bits
    unsigned u = __builtin_bit_cast(unsigned, f);
    u += 0x7fffu + ((u >> 16) & 1u);
    return (unsigned short)(u >> 16);
}

// ---------------------------------------------------------------------------
// Kernel 1 (merged halves): [U|V] = z @ W_combined (bf16 MFMA 16x16x32),
// int8 output with per-node fp32 scales. ONE pass over z (the half-split
// version read + decoded z twice).
//   W_combined[k][n] = n<128 ? W1[k][n] : W1[128+k][n-128]   (K=128, N=256)
// All 64 B-fragments staged once per block in LDS (exactly 64 KB).
// Epilogue: NO LDS transpose needed -- with the column-permuted int8 layout
//   dst[row*128 + mrow*8 + nt] = q(acc[nt][r])    (mrow = lane&15)
// lane (mrow,quad) natively holds the 8 contiguous bytes for its slot; a
// direct 8 B/lane store covers full 128-B lines per 16-lane group (no RMW).
// Edge kernel un-permutes for free via W2[j*16+p].
// Grid: 512 blocks = 2 blocks/CU exactly resident (64 KB LDS); grid-stride.
// ---------------------------------------------------------------------------
__global__ __launch_bounds__(256) void precompute_uv_mfma_q8(
    const float* __restrict__ z, const float* __restrict__ W1,
    const float* __restrict__ b1,
    signed char* __restrict__ U8, signed char* __restrict__ V8,
    float* __restrict__ u_scale, float* __restrict__ v_scale,
    int N, int nchunks)
{
    __shared__ unsigned short WsF[64 * 64 * 8];     // 64 KiB: B-frags, both halves

    const int t    = threadIdx.x;
    const int lane = t & 63;
    const int w    = t >> 6;            // wave 0..3

    // ---- stage all W fragments (once per block) ----
    {
        const int nlow = lane & 15;
        const int kq   = (lane >> 4) & 3;
        #pragma unroll
        for (int i = 0; i < 16; ++i) {
            const int ntks = w + i * 4;              // 0..63
            const int nt = ntks >> 2, ks = ntks & 3;
            const int n  = nt * 16 + nlow;           // combined col 0..255
            const int kb = ks * 32 + kq * 8;
            const float* __restrict__ wsrc = (n < DDIM)
                ? (W1 + (size_t)kb * DDIM + n)
                : (W1 + (size_t)(DDIM + kb) * DDIM + (n - DDIM));
            unsigned short frag[8];
            #pragma unroll
            for (int j = 0; j < 8; ++j)
                frag[j] = f2bf(wsrc[(size_t)j * DDIM]);
            *(uint4*)&WsF[(ntks * 64 + lane) * 8] = *(const uint4*)frag;
        }
    }
    __syncthreads();

    const int mrow = lane & 15;    // C/D col within 16-tile
    const int quad = lane >> 4;    // C/D row group

    // bias per nt (col = nt*16 + mrow); b1 applies to U cols (nt<8) only
    float bval[16];
    #pragma unroll
    for (int nt = 0; nt < 16; ++nt)
        bval[nt] = (nt < 8) ? b1[nt * 16 + mrow] : 0.f;

    for (int chunk = blockIdx.x; chunk < nchunks; chunk += gridDim.x) {
        const int m0 = chunk * 64 + w * 16;

        // A fragments: lane holds z[m0+mrow][ks*32 + quad*8 + j]  (decoded ONCE)
        bf16x8 afrag[4];
        {
            int grow = m0 + mrow; if (grow > N - 1) grow = N - 1;
            const float* zrow = z + (size_t)grow * DDIM;
            #pragma unroll
            for (int ks = 0; ks < 4; ++ks) {
                const int k0 = ks * 32 + quad * 8;
                const float4 x0 = *(const float4*)(zrow + k0);
                const float4 x1 = *(const float4*)(zrow + k0 + 4);
                unsigned short a[8];
                a[0] = f2bf(x0.x); a[1] = f2bf(x0.y); a[2] = f2bf(x0.z); a[3] = f2bf(x0.w);
                a[4] = f2bf(x1.x); a[5] = f2bf(x1.y); a[6] = f2bf(x1.z); a[7] = f2bf(x1.w);
                afrag[ks] = __builtin_bit_cast(bf16x8, *(const uint4*)a);
            }
        }

        floatx4 acc[16];
        #pragma unroll
        for (int nt = 0; nt < 16; ++nt) acc[nt] = (floatx4){0.f, 0.f, 0.f, 0.f};

        #pragma unroll
        for (int ks = 0; ks < 4; ++ks) {
            #pragma unroll
            for (int nt = 0; nt < 16; ++nt) {
                const bf16x8 b = __builtin_bit_cast(bf16x8,
                    *(const uint4*)&WsF[((nt * 4 + ks) * 64 + lane) * 8]);
                acc[nt] = __builtin_amdgcn_mfma_f32_16x16x32_bf16(afrag[ks], b, acc[nt], 0, 0, 0);
            }
        }

        // ---- quantize + direct permuted stores ----
        // C-layout: value (nt,r) -> local row quad*4+r, col nt*16+mrow.
        #pragma unroll
        for (int r = 0; r < 4; ++r) {
            float au = 0.f, av = 0.f;
            #pragma unroll
            for (int nt = 0; nt < 8; ++nt)  au = fmaxf(au, fabsf(acc[nt][r] + bval[nt]));
            #pragma unroll
            for (int nt = 8; nt < 16; ++nt) av = fmaxf(av, fabsf(acc[nt][r]));
            #pragma unroll
            for (int m = 1; m < 16; m <<= 1) {
                au = fmaxf(au, __shfl_xor(au, m, 16));
                av = fmaxf(av, __shfl_xor(av, m, 16));
            }
            au = fmaxf(au, 1e-20f); av = fmaxf(av, 1e-20f);
            const float iu = 127.f / au, iv = 127.f / av;

            unsigned char bu[8], bv[8];
            #pragma unroll
            for (int nt = 0; nt < 8; ++nt) {
                const int qu = (int)rintf((acc[nt][r] + bval[nt]) * iu);
                const int qv = (int)rintf(acc[nt + 8][r] * iv);
                bu[nt] = (unsigned char)(qu & 0xff);
                bv[nt] = (unsigned char)(qv & 0xff);
            }

            const int grow = chunk * 64 + w * 16 + quad * 4 + r;
            if (grow < N) {
                *(unsigned long long*)&U8[(size_t)grow * DDIM + mrow * 8] =
                    *(const unsigned long long*)bu;
                *(unsigned long long*)&V8[(size_t)grow * DDIM + mrow * 8] =
                    *(const unsigned long long*)bv;
                if (mrow == 0) {
                    u_scale[grow] = au * (1.f / 127.f);
                    v_scale[grow] = av * (1.f / 127.f);
                }
            }
        }
    }
}

// ---------------------------------------------------------------------------
// Kernel 2: per-edge gather (int8 U/V + per-node scales) + relu + dot(W2).
// 16 lanes per group, 4 edges per group. Lane p's 8 bytes are permuted cols
// j*16+p, so ww[j] = W2[j*16+p].
// ---------------------------------------------------------------------------
__global__ __launch_bounds__(256) void edge_kernel_i8(
    const int* __restrict__ ei,
    const signed char* __restrict__ U8, const signed char* __restrict__ V8,
    const float* __restrict__ u_scale, const float* __restrict__ v_scale,
    const float* __restrict__ W2, const float* __restrict__ b2,
    float* __restrict__ out, int E)
{
    const int t  = threadIdx.x;
    const int p  = t & 15;
    const int g0 = (blockIdx.x * 16 + (t >> 4)) * 4;   // first of 4 edges

    float ww[8];
    #pragma unroll
    for (int j = 0; j < 8; ++j) ww[j] = W2[j * 16 + p];

    if (g0 >= E) return;

    int rows[4], cols[4];
    if (g0 + 3 < E) {
        const int4 r4 = *(const int4*)(ei + g0);
        const int4 c4 = *(const int4*)(ei + (size_t)E + g0);
        rows[0]=r4.x; rows[1]=r4.y; rows[2]=r4.z; rows[3]=r4.w;
        cols[0]=c4.x; cols[1]=c4.y; cols[2]=c4.z; cols[3]=c4.w;
    } else {
        #pragma unroll
        for (int i = 0; i < 4; ++i) {
            const int gi = (g0 + i < E) ? (g0 + i) : (E - 1);
            rows[i] = ei[gi];
            cols[i] = ei[(size_t)E + gi];
        }
    }

    uint2 uu[4], vv[4];
    #pragma unroll
    for (int i = 0; i < 4; ++i)
        uu[i] = *(const uint2*)(U8 + (size_t)rows[i] * DDIM + p * 8);
    #pragma unroll
    for (int i = 0; i < 4; ++i)
        vv[i] = *(const uint2*)(V8 + (size_t)cols[i] * DDIM + p * 8);

    float su[4], sv[4];
    #pragma unroll
    for (int i = 0; i < 4; ++i) { su[i] = u_scale[rows[i]]; sv[i] = v_scale[cols[i]]; }

    const float bias = b2[0];

    #pragma unroll
    for (int i = 0; i < 4; ++i) {
        const signed char* us = (const signed char*)&uu[i];
        const signed char* vs = (const signed char*)&vv[i];
        float s = 0.f;
        #pragma unroll
        for (int j = 0; j < 8; ++j) {
            const float h = fmaf(sv[i], (float)vs[j], su[i] * (float)us[j]);
            s = fmaf(fmaxf(h, 0.f), ww[j], s);
        }
        #pragma unroll
        for (int off = 8; off > 0; off >>= 1)
            s += __shfl_down(s, off, 16);
        if (p == 0 && g0 + i < E) out[g0 + i] = s + bias;
    }
}

// ---------------------------------------------------------------------------
// Fallback (ws too small): fused per-edge fp32 GEMV (known-correct path).
// ---------------------------------------------------------------------------
__global__ __launch_bounds__(256) void edge_fused_fallback(
    const float* __restrict__ z, const int* __restrict__ ei,
    const float* __restrict__ W1, const float* __restrict__ b1,
    const float* __restrict__ W2, const float* __restrict__ b2,
    float* __restrict__ out, int N, int E)
{
    const int tid  = blockIdx.x * 256 + threadIdx.x;
    const int e    = tid >> 6;
    const int lane = tid & 63;
    if (e >= E) return;

    const int row = ei[e];
    const int col = ei[(size_t)E + e];
    const float* zr = z + (size_t)row * DDIM;
    const float* zc = z + (size_t)col * DDIM;

    float h0 = b1[lane];
    float h1 = b1[lane + 64];
    for (int k = 0; k < DDIM; ++k) {
        const float a = zr[k];
        const float b = zc[k];
        h0 = fmaf(a, W1[k * DDIM + lane],               h0);
        h0 = fmaf(b, W1[(DDIM + k) * DDIM + lane],      h0);
        h1 = fmaf(a, W1[k * DDIM + lane + 64],          h1);
        h1 = fmaf(b, W1[(DDIM + k) * DDIM + lane + 64], h1);
    }
    float s = fmaxf(h0, 0.f) * W2[lane] + fmaxf(h1, 0.f) * W2[lane + 64];
    #pragma unroll
    for (int off = 32; off > 0; off >>= 1)
        s += __shfl_down(s, off, 64);
    if (lane == 0) out[e] = s + b2[0];
}

extern "C" void kernel_launch(void* const* d_in, const int* in_sizes, int n_in,
                              void* d_out, int out_size, void* d_ws, size_t ws_size,
                              hipStream_t stream)
{
    const float* z  = (const float*)d_in[0];
    const int*   ei = (const int*)d_in[1];       // int32 per harness convention
    const float* W1 = (const float*)d_in[2];
    const float* b1 = (const float*)d_in[3];
    const float* W2 = (const float*)d_in[4];
    const float* b2 = (const float*)d_in[5];
    float*       out = (float*)d_out;

    const int N = in_sizes[0] / DDIM;
    const int E = in_sizes[1] / 2;

    const size_t n128 = (size_t)N * DDIM;
    const size_t need = 2 * n128 + 2 * (size_t)N * sizeof(float) + 256;
    if (ws_size >= need) {
        signed char* U8 = (signed char*)d_ws;
        signed char* V8 = U8 + n128;
        float* usc = (float*)(((size_t)(V8 + n128) + 255) & ~(size_t)255);
        float* vsc = usc + N;
        const int nchunks = (N + 63) / 64;
        // 512 blocks = 2 blocks/CU x 256 CUs (64 KB LDS each) fully resident.
        hipLaunchKernelGGL(precompute_uv_mfma_q8, dim3(512), dim3(256), 0, stream,
                           z, W1, b1, U8, V8, usc, vsc, N, nchunks);
        hipLaunchKernelGGL(edge_kernel_i8, dim3((E + 63) / 64), dim3(256), 0, stream,
                           ei, U8, V8, usc, vsc, W2, b2, out, E);
    } else {
        hipLaunchKernelGGL(edge_fused_fallback, dim3((E + 3) / 4), dim3(256), 0, stream,
                           z, ei, W1, b1, W2, b2, out, N, E);
    }
}

// Round 8
// 146.745 us; speedup vs baseline: 1.0454x; 1.0454x over previous
//
#include <hip/hip_runtime.h>

#define DDIM 128

typedef __bf16 bf16x8 __attribute__((ext_vector_type(8)));
typedef float  floatx4 __attribute__((ext_vector_type(4)));

__device__ inline unsigned short f2bf(float f) {      // RNE fp32 -> bf16 bits
    unsigned u = __builtin_bit_cast(unsigned, f);
    u += 0x7fffu + ((u >> 16) & 1u);
    return (unsigned short)(u >> 16);
}

// ---------------------------------------------------------------------------
// Kernel 0: one-shot swizzle of W1 into MFMA B-fragment order in global ws.
//   Wf[(f*64 + lane)*8 + j] = bf16(W_combined[kb+j][n]),
//   f = nt*4+ks (nt 0..15 -> combined col tile, ks 0..3 -> K step),
//   n = nt*16 + (lane&15), kb = ks*32 + (lane>>4)*8.
// 64 KB total; L2-resident afterwards. Lets the main kernel read B-frags as
// perfectly contiguous coalesced dwordx4 loads -> NO LDS, NO transpose
// staging, NO barriers in the main kernel (round-7 counters showed it was
// latency-bound at 2 waves/SIMD: Occ 8.9%, VALU 18%, Mfma 4.6%).
// ---------------------------------------------------------------------------
__global__ __launch_bounds__(256) void swizzle_w(
    const float* __restrict__ W1, unsigned short* __restrict__ Wf)
{
    const int id   = blockIdx.x * 256 + threadIdx.x;   // 0..4095
    const int f    = id >> 6;
    const int lane = id & 63;
    const int nt = f >> 2, ks = f & 3;
    const int n  = nt * 16 + (lane & 15);              // combined col 0..255
    const int kb = ks * 32 + (lane >> 4) * 8;
    const float* __restrict__ wsrc = (n < DDIM)
        ? (W1 + (size_t)kb * DDIM + n)
        : (W1 + (size_t)(DDIM + kb) * DDIM + (n - DDIM));
    unsigned short frag[8];
    #pragma unroll
    for (int j = 0; j < 8; ++j)
        frag[j] = f2bf(wsrc[(size_t)j * DDIM]);
    *(uint4*)&Wf[(size_t)id * 8] = *(const uint4*)frag;
}

// ---------------------------------------------------------------------------
// Kernel 1: [U|V] = z @ W_combined (bf16 MFMA 16x16x32), int8 out with
// per-node scales. One 64-row chunk per block; B-frags straight from the
// pre-swizzled global buffer (L2-hot). U cols (nt 0..7) and V cols (nt 8..15)
// processed sequentially reusing the same A-frags -> 32 acc VGPRs live.
// launch_bounds(...,3) pins allocator to >=3 waves/SIMD.
// Output stores use the column-permuted int8 layout (8 contiguous B/lane,
// full 128-B lines per 16-lane group); edge kernel un-permutes via W2[j*16+p].
// ---------------------------------------------------------------------------
__global__ __launch_bounds__(256, 3) void precompute_uv_mfma_q8(
    const float* __restrict__ z, const unsigned short* __restrict__ Wf,
    const float* __restrict__ b1,
    signed char* __restrict__ U8, signed char* __restrict__ V8,
    float* __restrict__ u_scale, float* __restrict__ v_scale,
    int N)
{
    const int lane = threadIdx.x & 63;
    const int w    = threadIdx.x >> 6;       // wave 0..3
    const int mrow = lane & 15;
    const int quad = lane >> 4;
    const int m0   = blockIdx.x * 64 + w * 16;

    // A fragments: lane holds z[m0+mrow][ks*32 + quad*8 + j]
    bf16x8 afrag[4];
    {
        int grow = m0 + mrow; if (grow > N - 1) grow = N - 1;
        const float* zrow = z + (size_t)grow * DDIM;
        #pragma unroll
        for (int ks = 0; ks < 4; ++ks) {
            const int k0 = ks * 32 + quad * 8;
            const float4 x0 = *(const float4*)(zrow + k0);
            const float4 x1 = *(const float4*)(zrow + k0 + 4);
            unsigned short a[8];
            a[0] = f2bf(x0.x); a[1] = f2bf(x0.y); a[2] = f2bf(x0.z); a[3] = f2bf(x0.w);
            a[4] = f2bf(x1.x); a[5] = f2bf(x1.y); a[6] = f2bf(x1.z); a[7] = f2bf(x1.w);
            afrag[ks] = __builtin_bit_cast(bf16x8, *(const uint4*)a);
        }
    }

    #pragma unroll
    for (int half = 0; half < 2; ++half) {
        signed char* __restrict__ dst8 = half ? V8 : U8;
        float*       __restrict__ dscl = half ? v_scale : u_scale;

        float bval[8];
        #pragma unroll
        for (int nt = 0; nt < 8; ++nt)
            bval[nt] = half ? 0.f : b1[nt * 16 + mrow];

        floatx4 acc[8];
        #pragma unroll
        for (int nt = 0; nt < 8; ++nt) acc[nt] = (floatx4){0.f, 0.f, 0.f, 0.f};

        const unsigned short* __restrict__ wbase =
            Wf + ((size_t)half * 32 * 64) * 8 + (size_t)lane * 8;

        #pragma unroll
        for (int ks = 0; ks < 4; ++ks) {
            #pragma unroll
            for (int nt = 0; nt < 8; ++nt) {
                const bf16x8 b = __builtin_bit_cast(bf16x8,
                    *(const uint4*)(wbase + (size_t)((nt * 4 + ks) * 64) * 8));
                acc[nt] = __builtin_amdgcn_mfma_f32_16x16x32_bf16(afrag[ks], b, acc[nt], 0, 0, 0);
            }
        }

        // quantize epilogue; C-layout: (nt,r) -> local row quad*4+r, col nt*16+mrow
        #pragma unroll
        for (int r = 0; r < 4; ++r) {
            float mx = 0.f;
            #pragma unroll
            for (int nt = 0; nt < 8; ++nt)
                mx = fmaxf(mx, fabsf(acc[nt][r] + bval[nt]));
            #pragma unroll
            for (int m = 1; m < 16; m <<= 1)
                mx = fmaxf(mx, __shfl_xor(mx, m, 16));
            mx = fmaxf(mx, 1e-20f);
            const float inv = 127.f / mx;

            unsigned char bytes[8];
            #pragma unroll
            for (int nt = 0; nt < 8; ++nt) {
                const int q = (int)rintf((acc[nt][r] + bval[nt]) * inv);
                bytes[nt] = (unsigned char)(q & 0xff);
            }
            const int grow = m0 + quad * 4 + r;
            if (grow < N) {
                *(unsigned long long*)&dst8[(size_t)grow * DDIM + mrow * 8] =
                    *(const unsigned long long*)bytes;
                if (mrow == 0) dscl[grow] = mx * (1.f / 127.f);
            }
        }
    }
}

// ---------------------------------------------------------------------------
// Kernel 2: per-edge gather (int8 U/V + per-node scales) + relu + dot(W2).
// 16 lanes per group, 4 edges per group. Lane p's 8 bytes are permuted cols
// j*16+p, so ww[j] = W2[j*16+p].
// ---------------------------------------------------------------------------
__global__ __launch_bounds__(256) void edge_kernel_i8(
    const int* __restrict__ ei,
    const signed char* __restrict__ U8, const signed char* __restrict__ V8,
    const float* __restrict__ u_scale, const float* __restrict__ v_scale,
    const float* __restrict__ W2, const float* __restrict__ b2,
    float* __restrict__ out, int E)
{
    const int t  = threadIdx.x;
    const int p  = t & 15;
    const int g0 = (blockIdx.x * 16 + (t >> 4)) * 4;   // first of 4 edges

    float ww[8];
    #pragma unroll
    for (int j = 0; j < 8; ++j) ww[j] = W2[j * 16 + p];

    if (g0 >= E) return;

    int rows[4], cols[4];
    if (g0 + 3 < E) {
        const int4 r4 = *(const int4*)(ei + g0);
        const int4 c4 = *(const int4*)(ei + (size_t)E + g0);
        rows[0]=r4.x; rows[1]=r4.y; rows[2]=r4.z; rows[3]=r4.w;
        cols[0]=c4.x; cols[1]=c4.y; cols[2]=c4.z; cols[3]=c4.w;
    } else {
        #pragma unroll
        for (int i = 0; i < 4; ++i) {
            const int gi = (g0 + i < E) ? (g0 + i) : (E - 1);
            rows[i] = ei[gi];
            cols[i] = ei[(size_t)E + gi];
        }
    }

    uint2 uu[4], vv[4];
    #pragma unroll
    for (int i = 0; i < 4; ++i)
        uu[i] = *(const uint2*)(U8 + (size_t)rows[i] * DDIM + p * 8);
    #pragma unroll
    for (int i = 0; i < 4; ++i)
        vv[i] = *(const uint2*)(V8 + (size_t)cols[i] * DDIM + p * 8);

    float su[4], sv[4];
    #pragma unroll
    for (int i = 0; i < 4; ++i) { su[i] = u_scale[rows[i]]; sv[i] = v_scale[cols[i]]; }

    const float bias = b2[0];

    #pragma unroll
    for (int i = 0; i < 4; ++i) {
        const signed char* us = (const signed char*)&uu[i];
        const signed char* vs = (const signed char*)&vv[i];
        float s = 0.f;
        #pragma unroll
        for (int j = 0; j < 8; ++j) {
            const float h = fmaf(sv[i], (float)vs[j], su[i] * (float)us[j]);
            s = fmaf(fmaxf(h, 0.f), ww[j], s);
        }
        #pragma unroll
        for (int off = 8; off > 0; off >>= 1)
            s += __shfl_down(s, off, 16);
        if (p == 0 && g0 + i < E) out[g0 + i] = s + bias;
    }
}

// ---------------------------------------------------------------------------
// Fallback (ws too small): fused per-edge fp32 GEMV (known-correct path).
// ---------------------------------------------------------------------------
__global__ __launch_bounds__(256) void edge_fused_fallback(
    const float* __restrict__ z, const int* __restrict__ ei,
    const float* __restrict__ W1, const float* __restrict__ b1,
    const float* __restrict__ W2, const float* __restrict__ b2,
    float* __restrict__ out, int N, int E)
{
    const int tid  = blockIdx.x * 256 + threadIdx.x;
    const int e    = tid >> 6;
    const int lane = tid & 63;
    if (e >= E) return;

    const int row = ei[e];
    const int col = ei[(size_t)E + e];
    const float* zr = z + (size_t)row * DDIM;
    const float* zc = z + (size_t)col * DDIM;

    float h0 = b1[lane];
    float h1 = b1[lane + 64];
    for (int k = 0; k < DDIM; ++k) {
        const float a = zr[k];
        const float b = zc[k];
        h0 = fmaf(a, W1[k * DDIM + lane],               h0);
        h0 = fmaf(b, W1[(DDIM + k) * DDIM + lane],      h0);
        h1 = fmaf(a, W1[k * DDIM + lane + 64],          h1);
        h1 = fmaf(b, W1[(DDIM + k) * DDIM + lane + 64], h1);
    }
    float s = fmaxf(h0, 0.f) * W2[lane] + fmaxf(h1, 0.f) * W2[lane + 64];
    #pragma unroll
    for (int off = 32; off > 0; off >>= 1)
        s += __shfl_down(s, off, 64);
    if (lane == 0) out[e] = s + b2[0];
}

extern "C" void kernel_launch(void* const* d_in, const int* in_sizes, int n_in,
                              void* d_out, int out_size, void* d_ws, size_t ws_size,
                              hipStream_t stream)
{
    const float* z  = (const float*)d_in[0];
    const int*   ei = (const int*)d_in[1];       // int32 per harness convention
    const float* W1 = (const float*)d_in[2];
    const float* b1 = (const float*)d_in[3];
    const float* W2 = (const float*)d_in[4];
    const float* b2 = (const float*)d_in[5];
    float*       out = (float*)d_out;

    const int N = in_sizes[0] / DDIM;
    const int E = in_sizes[1] / 2;

    const size_t n128 = (size_t)N * DDIM;
    const size_t need = 2 * n128 + 2 * (size_t)N * sizeof(float)
                      + 64 * 1024 + 512;
    if (ws_size >= need) {
        signed char* U8 = (signed char*)d_ws;
        signed char* V8 = U8 + n128;
        float* usc = (float*)(((size_t)(V8 + n128) + 255) & ~(size_t)255);
        float* vsc = usc + N;
        unsigned short* Wf = (unsigned short*)(((size_t)(vsc + N) + 255) & ~(size_t)255);

        hipLaunchKernelGGL(swizzle_w, dim3(16), dim3(256), 0, stream, W1, Wf);
        hipLaunchKernelGGL(precompute_uv_mfma_q8, dim3((N + 63) / 64), dim3(256), 0, stream,
                           z, Wf, b1, U8, V8, usc, vsc, N);
        hipLaunchKernelGGL(edge_kernel_i8, dim3((E + 63) / 64), dim3(256), 0, stream,
                           ei, U8, V8, usc, vsc, W2, b2, out, E);
    } else {
        hipLaunchKernelGGL(edge_fused_fallback, dim3((E + 3) / 4), dim3(256), 0, stream,
                           z, ei, W1, b1, W2, b2, out, N, E);
    }
}